// Round 3
// baseline (3745.921 us; speedup 1.0000x reference)
//
#include <hip/hip_runtime.h>

typedef __attribute__((ext_vector_type(8))) short bf16x8;
typedef __attribute__((ext_vector_type(4))) float f32x4;

#define MFMA16(a, b, c) __builtin_amdgcn_mfma_f32_16x16x32_bf16((a), (b), (c), 0, 0, 0)

__device__ __forceinline__ unsigned short f2bf(float f) {
    unsigned int u = __builtin_bit_cast(unsigned int, f);
    u = (u + 0x7fffu + ((u >> 16) & 1u)) >> 16;
    return (unsigned short)u;
}
__device__ __forceinline__ float bf2f(unsigned short s) {
    unsigned int u = ((unsigned int)s) << 16;
    return __builtin_bit_cast(float, u);
}
__device__ __forceinline__ bf16x8 pack8(float4 a, float4 b) {
    bf16x8 v;
    v[0] = (short)f2bf(a.x); v[1] = (short)f2bf(a.y);
    v[2] = (short)f2bf(a.z); v[3] = (short)f2bf(a.w);
    v[4] = (short)f2bf(b.x); v[5] = (short)f2bf(b.y);
    v[6] = (short)f2bf(b.z); v[7] = (short)f2bf(b.w);
    return v;
}
__device__ __forceinline__ float sigmoidf_(float x) { return 1.0f / (1.0f + __expf(-x)); }
__device__ __forceinline__ float tanhf_(float x) { return 2.0f / (1.0f + __expf(-2.0f * x)) - 1.0f; }

// ---------------- elementwise f32 -> bf16 convert ----------------
__global__ void k_cvt(const float* __restrict__ s, unsigned short* __restrict__ d, int n8) {
    int i = blockIdx.x * blockDim.x + threadIdx.x;
    int stride = gridDim.x * blockDim.x;
    for (; i < n8; i += stride) {
        const float4* sp = (const float4*)(s + (size_t)i * 8);
        float4 a = sp[0], b = sp[1];
        *(bf16x8*)(d + (size_t)i * 8) = pack8(a, b);
    }
}

// ---------------- transpose enc [b][s][h] -> [b][h][s] (bf16) ----------------
__global__ void k_transpose(const unsigned short* __restrict__ src, unsigned short* __restrict__ dst) {
    __shared__ unsigned short tile[64][66];
    const int b = blockIdx.x, s0 = blockIdx.y * 64, h0 = blockIdx.z * 64;
    const int tx = threadIdx.x, ty = threadIdx.y;
    for (int r = ty; r < 64; r += 4)
        tile[r][tx] = src[((size_t)(b * 512) + (s0 + r)) * 512 + h0 + tx];
    __syncthreads();
    for (int r = ty; r < 64; r += 4)
        dst[((size_t)(b * 512) + (h0 + r)) * 512 + s0 + tx] = tile[tx][r];
}

// ---------------- K1: xi = emb @ W_ih^T + b_ih  (bf16 out) ----------------
__global__ __launch_bounds__(256) void k_gemm_xi(
    const float* __restrict__ emb, const float* __restrict__ W_ih,
    const float* __restrict__ b_ih, unsigned short* __restrict__ xi) {
    __shared__ unsigned short Asub[2][4096];
    __shared__ unsigned short Bsub[2][4096];
    const int tid = threadIdx.x;
    const int wv = tid >> 6, l = tid & 63, lr = l & 15, lu = l >> 4;
    const int wm = wv >> 1, wn = wv & 1;
    const int row0 = blockIdx.x * 128, col0 = blockIdx.y * 128;

    f32x4 acc[4][4];
#pragma unroll
    for (int mt = 0; mt < 4; ++mt)
#pragma unroll
        for (int nt = 0; nt < 4; ++nt) acc[mt][nt] = (f32x4){0.f, 0.f, 0.f, 0.f};

    bf16x8 sA[2], sB[2];
    auto ldstage = [&](int ks) {
#pragma unroll
        for (int i = 0; i < 2; ++i) {
            int chunk = i * 256 + tid;
            int row = chunk >> 2;
            int ce = (chunk & 3) * 8;
            const float* pa = emb + (size_t)(row0 + row) * 512 + ks * 32 + ce;
            sA[i] = pack8(((const float4*)pa)[0], ((const float4*)pa)[1]);
            const float* pb = W_ih + (size_t)(col0 + row) * 512 + ks * 32 + ce;
            sB[i] = pack8(((const float4*)pb)[0], ((const float4*)pb)[1]);
        }
    };
    auto wrstage = [&](int buf) {
#pragma unroll
        for (int i = 0; i < 2; ++i) {
            int chunk = i * 256 + tid;
            int idx = (chunk & 3) * 1024 + (chunk >> 2) * 8;
            *(bf16x8*)(&Asub[buf][idx]) = sA[i];
            *(bf16x8*)(&Bsub[buf][idx]) = sB[i];
        }
    };
    ldstage(0);
    wrstage(0);
    __syncthreads();
#pragma unroll 1
    for (int ks = 0; ks < 16; ++ks) {
        const int cb = ks & 1;
        if (ks < 15) ldstage(ks + 1);
        bf16x8 af[4];
#pragma unroll
        for (int mt = 0; mt < 4; ++mt)
            af[mt] = *(const bf16x8*)(&Asub[cb][lu * 1024 + (wm * 64 + mt * 16 + lr) * 8]);
#pragma unroll
        for (int nt = 0; nt < 4; ++nt) {
            bf16x8 bb = *(const bf16x8*)(&Bsub[cb][lu * 1024 + (wn * 64 + nt * 16 + lr) * 8]);
#pragma unroll
            for (int mt = 0; mt < 4; ++mt) acc[mt][nt] = MFMA16(af[mt], bb, acc[mt][nt]);
        }
        if (ks < 15) wrstage(cb ^ 1);
        __syncthreads();
    }
#pragma unroll
    for (int nt = 0; nt < 4; ++nt) {
        const int col = col0 + wn * 64 + nt * 16 + lr;
        const float bias = b_ih[col];
#pragma unroll
        for (int mt = 0; mt < 4; ++mt)
#pragma unroll
            for (int j = 0; j < 4; ++j) {
                const int row = row0 + wm * 64 + mt * 16 + lu * 4 + j;
                xi[(size_t)row * 1536 + col] = f2bf(acc[mt][nt][j] + bias);
            }
    }
}

// ---------------- K2: GRU scan. 16 persistent WGs = 4 batch-groups x 4 N-slices. ----------------
// launch_bounds(512,2): min 2 waves/EU -> 256-VGPR cap -> 192-reg weight file stays resident.
// Per-producer flag words (store-release), per-wave relaxed polling + acquire pairing.
__global__ __launch_bounds__(512, 2) void k_scan(
    const float* __restrict__ W_hh, const float* __restrict__ b_hh,
    const unsigned short* __restrict__ xi,
    unsigned short* __restrict__ dec, float* __restrict__ hlast,
    unsigned short* hb,            // [4][2][16][512] bf16
    unsigned int* flags) {         // [4][512][4]
    __shared__ unsigned short hlds[16 * 512];    // 16 KB, XOR-swizzled A-tile
    __shared__ unsigned short hstage[16 * 128];  // 4 KB, XOR-swizzled
    const int tid = threadIdx.x;
    const int w = tid >> 6, l = tid & 63, lr = l & 15, lu = l >> 4;
    const int g = blockIdx.x & 3;   // batch group
    const int q = blockIdx.x >> 2;  // N-slice
    const int bg0 = g * 16;
    const int hcol = q * 128 + w * 16 + lr;
    unsigned short* hb_g = hb + g * 16384;
    unsigned int* flag_g = flags + g * 2048;
    const int myword = (tid & 127) >> 5;  // which producer slice this thread's h-loads come from

    // preload W_hh fragments: 3 gates x 16 k-tiles (192 VGPR)
    bf16x8 wf[3][16];
#pragma unroll
    for (int g3 = 0; g3 < 3; ++g3) {
        const float* wr = W_hh + (size_t)(g3 * 512 + hcol) * 512;
#pragma unroll
        for (int kt = 0; kt < 16; ++kt) {
            const float* p = wr + kt * 32 + lu * 8;
            wf[g3][kt] = pack8(*(const float4*)p, *(const float4*)(p + 4));
        }
    }
    float bh[3];
#pragma unroll
    for (int g3 = 0; g3 < 3; ++g3) bh[g3] = b_hh[g3 * 512 + hcol];

    // prefetch xi for t=0
    unsigned short xv[12];
#pragma unroll
    for (int g3 = 0; g3 < 3; ++g3)
#pragma unroll
        for (int j = 0; j < 4; ++j)
            xv[g3 * 4 + j] = xi[((size_t)(bg0 + lu * 4 + j) * 512 + 0) * 1536 + g3 * 512 + hcol];

    float hloc[4] = {0.f, 0.f, 0.f, 0.f};

#pragma clang loop unroll(disable)
    for (int t = 0; t < 512; ++t) {
        // wait for previous step's producer of MY slice (per-wave poll, no tid0 fan-out)
        if (t > 0) {
            const unsigned int* fp = &flag_g[(t - 1) * 4 + myword];
            while (true) {
                unsigned int v = __hip_atomic_load(fp, __ATOMIC_RELAXED, __HIP_MEMORY_SCOPE_AGENT);
                if (__all(v != 0)) break;
                __builtin_amdgcn_s_sleep(1);
            }
            unsigned int vv = __hip_atomic_load(fp, __ATOMIC_ACQUIRE, __HIP_MEMORY_SCOPE_AGENT);
            asm volatile("" ::"v"(vv));  // keep the acquire load live
        }
        // cooperative coherent load of h (16 KB) -> swizzled LDS
        {
            unsigned long long* src = (unsigned long long*)(hb_g + (t & 1) * 8192);
#pragma unroll
            for (int i = 0; i < 4; ++i) {
                int c = i * 512 + tid;
                unsigned long long v = __hip_atomic_load(src + c, __ATOMIC_RELAXED, __HIP_MEMORY_SCOPE_AGENT);
                int row = c >> 7;
                int colb = (c & 127) * 8;
                *(unsigned long long*)((char*)hlds + row * 1024 + (colb ^ ((row & 7) << 4))) = v;
            }
        }
        __syncthreads();
        // MFMA: h[16x512] @ W_slice^T -> 3 gate pre-activations (16x16 tile per wave)
        f32x4 acc0 = (f32x4){0.f, 0.f, 0.f, 0.f};
        f32x4 acc1 = (f32x4){0.f, 0.f, 0.f, 0.f};
        f32x4 acc2 = (f32x4){0.f, 0.f, 0.f, 0.f};
#pragma unroll
        for (int kt = 0; kt < 16; ++kt) {
            bf16x8 a = *(const bf16x8*)((char*)hlds + lr * 1024 + ((kt * 64 + lu * 16) ^ ((lr & 7) << 4)));
            acc0 = MFMA16(a, wf[0][kt], acc0);
            acc1 = MFMA16(a, wf[1][kt], acc1);
            acc2 = MFMA16(a, wf[2][kt], acc2);
        }
        // gates + state update (f32); write h_new to hstage (swizzled)
#pragma unroll
        for (int j = 0; j < 4; ++j) {
            float xr = bf2f(xv[0 * 4 + j]);
            float xz = bf2f(xv[1 * 4 + j]);
            float xn = bf2f(xv[2 * 4 + j]);
            float rr = sigmoidf_(xr + acc0[j] + bh[0]);
            float zz = sigmoidf_(xz + acc1[j] + bh[1]);
            float nn = tanhf_(xn + rr * (acc2[j] + bh[2]));
            float hv = (1.f - zz) * nn + zz * hloc[j];
            hloc[j] = hv;
            int row = lu * 4 + j;
            int colb = (w * 32 + lr * 2) ^ ((row & 7) << 4);
            *(unsigned short*)((char*)hstage + row * 256 + colb) = f2bf(hv);
            if (t == 511) hlast[(size_t)(bg0 + row) * 512 + hcol] = hv;
        }
        // prefetch xi for t+1 (latency hidden by store+sync+spin+load of next step)
        if (t < 511) {
#pragma unroll
            for (int g3 = 0; g3 < 3; ++g3)
#pragma unroll
                for (int j = 0; j < 4; ++j)
                    xv[g3 * 4 + j] = xi[((size_t)(bg0 + lu * 4 + j) * 512 + (t + 1)) * 1536 + g3 * 512 + hcol];
        }
        __syncthreads();
        // cooperative stores: h slice (coherent) + dec (plain)
        {
            int r = tid >> 5, c8 = tid & 31;
            unsigned long long v = *(unsigned long long*)((char*)hstage + r * 256 + ((c8 * 8) ^ ((r & 7) << 4)));
            if (t < 511)
                __hip_atomic_store(
                    (unsigned long long*)(hb_g + ((t + 1) & 1) * 8192 + r * 512 + q * 128) + c8, v,
                    __ATOMIC_RELAXED, __HIP_MEMORY_SCOPE_AGENT);
            *((unsigned long long*)(dec + ((size_t)(bg0 + r) * 512 + t) * 512 + q * 128) + c8) = v;
        }
        __syncthreads();  // drains vmcnt -> all threads' stores complete before flag
        if (t < 511 && tid == 0)
            __hip_atomic_store(&flag_g[t * 4 + q], 1u, __ATOMIC_RELEASE, __HIP_MEMORY_SCOPE_AGENT);
    }
}

// ---------------- K3: fused scores + softmax + mix, per (b, 64-row t tile) ----------------
__global__ __launch_bounds__(256) void k_attn(
    const unsigned short* __restrict__ dec, const unsigned short* __restrict__ enc,
    const unsigned short* __restrict__ encT, const unsigned char* __restrict__ masks,
    unsigned short* __restrict__ mix) {
    __shared__ char Pt[65536];
    __shared__ float red[64][4];
    const int tid = threadIdx.x, w = tid >> 6, l = tid & 63, lr = l & 15, lu = l >> 4;
    const int b = blockIdx.x >> 3, t0 = (blockIdx.x & 7) << 6;
    const size_t encBase = (size_t)b * 512 * 512;

    {   // stage dec tile (swizzled)
        const char* src = (const char*)(dec + (size_t)(b * 512 + t0) * 512);
#pragma unroll
        for (int i = 0; i < 16; ++i) {
            int chunk = i * 256 + tid;
            int row = chunk >> 6;
            int colb = (chunk & 63) * 16;
            uint4 v = *(const uint4*)(src + (size_t)row * 1024 + colb);
            *(uint4*)(Pt + row * 1024 + (colb ^ ((row & 7) << 4))) = v;
        }
    }
    __syncthreads();

    f32x4 acc[4][8];
#pragma unroll
    for (int mt = 0; mt < 4; ++mt)
#pragma unroll
        for (int nt = 0; nt < 8; ++nt) acc[mt][nt] = (f32x4){0.f, 0.f, 0.f, 0.f};

#pragma unroll 2
    for (int kt = 0; kt < 16; ++kt) {
        bf16x8 af[4];
#pragma unroll
        for (int mt = 0; mt < 4; ++mt)
            af[mt] = *(const bf16x8*)(Pt + (mt * 16 + lr) * 1024 + ((kt * 64 + lu * 16) ^ ((lr & 7) << 4)));
#pragma unroll
        for (int nt = 0; nt < 8; ++nt) {
            bf16x8 bb = *(const bf16x8*)(enc + encBase + (size_t)(w * 128 + nt * 16 + lr) * 512 + kt * 32 + lu * 8);
#pragma unroll
            for (int mt = 0; mt < 4; ++mt) acc[mt][nt] = MFMA16(af[mt], bb, acc[mt][nt]);
        }
    }
    // mask (True = masked)
#pragma unroll
    for (int nt = 0; nt < 8; ++nt) {
        if (masks[b * 512 + w * 128 + nt * 16 + lr]) {
#pragma unroll
            for (int mt = 0; mt < 4; ++mt)
#pragma unroll
                for (int j = 0; j < 4; ++j) acc[mt][nt][j] = -3.0e38f;
        }
    }
    // softmax over s (512 = 4 waves x 128)
    float rmax[4][4], rinv[4][4];
#pragma unroll
    for (int mt = 0; mt < 4; ++mt)
#pragma unroll
        for (int j = 0; j < 4; ++j) {
            float m = acc[mt][0][j];
#pragma unroll
            for (int nt = 1; nt < 8; ++nt) m = fmaxf(m, acc[mt][nt][j]);
            m = fmaxf(m, __shfl_xor(m, 1));
            m = fmaxf(m, __shfl_xor(m, 2));
            m = fmaxf(m, __shfl_xor(m, 4));
            m = fmaxf(m, __shfl_xor(m, 8));
            if (lr == 0) red[mt * 16 + lu * 4 + j][w] = m;
        }
    __syncthreads();
#pragma unroll
    for (int mt = 0; mt < 4; ++mt)
#pragma unroll
        for (int j = 0; j < 4; ++j) {
            float4 v = *(const float4*)(&red[mt * 16 + lu * 4 + j][0]);
            rmax[mt][j] = fmaxf(fmaxf(v.x, v.y), fmaxf(v.z, v.w));
        }
    __syncthreads();
#pragma unroll
    for (int mt = 0; mt < 4; ++mt)
#pragma unroll
        for (int j = 0; j < 4; ++j) {
            float s = 0.f;
#pragma unroll
            for (int nt = 0; nt < 8; ++nt) {
                float e = __expf(acc[mt][nt][j] - rmax[mt][j]);
                acc[mt][nt][j] = e;
                s += e;
            }
            s += __shfl_xor(s, 1);
            s += __shfl_xor(s, 2);
            s += __shfl_xor(s, 4);
            s += __shfl_xor(s, 8);
            if (lr == 0) red[mt * 16 + lu * 4 + j][w] = s;
        }
    __syncthreads();
#pragma unroll
    for (int mt = 0; mt < 4; ++mt)
#pragma unroll
        for (int j = 0; j < 4; ++j) {
            float4 v = *(const float4*)(&red[mt * 16 + lu * 4 + j][0]);
            rinv[mt][j] = 1.f / (v.x + v.y + v.z + v.w);
        }
    // write P (bf16) into Pt (swizzled)
#pragma unroll
    for (int mt = 0; mt < 4; ++mt)
#pragma unroll
        for (int nt = 0; nt < 8; ++nt)
#pragma unroll
            for (int j = 0; j < 4; ++j) {
                int row = mt * 16 + lu * 4 + j;
                int colb = (w * 128 + nt * 16 + lr) * 2;
                *(unsigned short*)(Pt + row * 1024 + (colb ^ ((row & 7) << 4))) =
                    f2bf(acc[mt][nt][j] * rinv[mt][j]);
            }
    __syncthreads();
    // mix = P @ enc  (B from encT, B^T layout)
#pragma unroll
    for (int mt = 0; mt < 4; ++mt)
#pragma unroll
        for (int nt = 0; nt < 8; ++nt) acc[mt][nt] = (f32x4){0.f, 0.f, 0.f, 0.f};
#pragma unroll 2
    for (int kt = 0; kt < 16; ++kt) {
        bf16x8 af[4];
#pragma unroll
        for (int mt = 0; mt < 4; ++mt)
            af[mt] = *(const bf16x8*)(Pt + (mt * 16 + lr) * 1024 + ((kt * 64 + lu * 16) ^ ((lr & 7) << 4)));
#pragma unroll
        for (int nt = 0; nt < 8; ++nt) {
            bf16x8 bb = *(const bf16x8*)(encT + encBase + (size_t)(w * 128 + nt * 16 + lr) * 512 + kt * 32 + lu * 8);
#pragma unroll
            for (int mt = 0; mt < 4; ++mt) acc[mt][nt] = MFMA16(af[mt], bb, acc[mt][nt]);
        }
    }
#pragma unroll
    for (int mt = 0; mt < 4; ++mt)
#pragma unroll
        for (int nt = 0; nt < 8; ++nt)
#pragma unroll
            for (int j = 0; j < 4; ++j) {
                int row = mt * 16 + lu * 4 + j, col = w * 128 + nt * 16 + lr;
                mix[(size_t)(b * 512 + t0 + row) * 512 + col] = f2bf(acc[mt][nt][j]);
            }
}

// ---------------- K4: out = tanh([mix,dec] @ Wa^T + ba) @ Wd^T + bd ----------------
__global__ __launch_bounds__(256) void k_out(
    const unsigned short* __restrict__ mix, const unsigned short* __restrict__ dec,
    const unsigned short* __restrict__ Wa, const float* __restrict__ ba,
    const unsigned short* __restrict__ Wd, const float* __restrict__ bd,
    float* __restrict__ out) {
    __shared__ char At[65536];
    const int tid = threadIdx.x, w = tid >> 6, l = tid & 63, lr = l & 15, lu = l >> 4;
    const int b = blockIdx.x >> 3, t0 = (blockIdx.x & 7) << 6;

    f32x4 acc[4][8];
#pragma unroll
    for (int mt = 0; mt < 4; ++mt)
#pragma unroll
        for (int nt = 0; nt < 8; ++nt) acc[mt][nt] = (f32x4){0.f, 0.f, 0.f, 0.f};

#pragma unroll 1
    for (int half = 0; half < 2; ++half) {
        const unsigned short* srcp = half ? dec : mix;
        const char* src = (const char*)(srcp + (size_t)(b * 512 + t0) * 512);
#pragma unroll
        for (int i = 0; i < 16; ++i) {
            int chunk = i * 256 + tid;
            int row = chunk >> 6;
            int colb = (chunk & 63) * 16;
            uint4 v = *(const uint4*)(src + (size_t)row * 1024 + colb);
            *(uint4*)(At + row * 1024 + (colb ^ ((row & 7) << 4))) = v;
        }
        __syncthreads();
#pragma unroll 2
        for (int kt = 0; kt < 16; ++kt) {
            bf16x8 af[4];
#pragma unroll
            for (int mt = 0; mt < 4; ++mt)
                af[mt] = *(const bf16x8*)(At + (mt * 16 + lr) * 1024 + ((kt * 64 + lu * 16) ^ ((lr & 7) << 4)));
#pragma unroll
            for (int nt = 0; nt < 8; ++nt) {
                bf16x8 bb = *(const bf16x8*)(Wa + (size_t)(w * 128 + nt * 16 + lr) * 1024 + half * 512 + kt * 32 + lu * 8);
#pragma unroll
                for (int mt = 0; mt < 4; ++mt) acc[mt][nt] = MFMA16(af[mt], bb, acc[mt][nt]);
            }
        }
        __syncthreads();
    }
    // tanh epilogue -> bf16 into At
    float bav[8];
#pragma unroll
    for (int nt = 0; nt < 8; ++nt) bav[nt] = ba[w * 128 + nt * 16 + lr];
#pragma unroll
    for (int mt = 0; mt < 4; ++mt)
#pragma unroll
        for (int nt = 0; nt < 8; ++nt)
#pragma unroll
            for (int j = 0; j < 4; ++j) {
                float v = tanhf_(acc[mt][nt][j] + bav[nt]);
                int row = mt * 16 + lu * 4 + j;
                int colb = (w * 128 + nt * 16 + lr) * 2;
                *(unsigned short*)(At + row * 1024 + (colb ^ ((row & 7) << 4))) = f2bf(v);
            }
    __syncthreads();
    // dense
#pragma unroll
    for (int mt = 0; mt < 4; ++mt)
#pragma unroll
        for (int nt = 0; nt < 8; ++nt) acc[mt][nt] = (f32x4){0.f, 0.f, 0.f, 0.f};
#pragma unroll 2
    for (int kt = 0; kt < 16; ++kt) {
        bf16x8 af[4];
#pragma unroll
        for (int mt = 0; mt < 4; ++mt)
            af[mt] = *(const bf16x8*)(At + (mt * 16 + lr) * 1024 + ((kt * 64 + lu * 16) ^ ((lr & 7) << 4)));
#pragma unroll
        for (int nt = 0; nt < 8; ++nt) {
            bf16x8 bb = *(const bf16x8*)(Wd + (size_t)(w * 128 + nt * 16 + lr) * 512 + kt * 32 + lu * 8);
#pragma unroll
            for (int mt = 0; mt < 4; ++mt) acc[mt][nt] = MFMA16(af[mt], bb, acc[mt][nt]);
        }
    }
#pragma unroll
    for (int nt = 0; nt < 8; ++nt) {
        const int col = w * 128 + nt * 16 + lr;
        const float bdv = bd[col];
#pragma unroll
        for (int mt = 0; mt < 4; ++mt)
#pragma unroll
            for (int j = 0; j < 4; ++j) {
                int row = mt * 16 + lu * 4 + j;
                out[(size_t)(b * 512 + t0 + row) * 512 + col] = acc[mt][nt][j] + bdv;
            }
    }
}

extern "C" void kernel_launch(void* const* d_in, const int* in_sizes, int n_in,
                              void* d_out, int out_size, void* d_ws, size_t ws_size,
                              hipStream_t stream) {
    const float* emb = (const float*)d_in[0];
    const float* enc_f = (const float*)d_in[1];
    const unsigned char* masks = (const unsigned char*)d_in[2];
    const float* W_ih = (const float*)d_in[3];
    const float* W_hh = (const float*)d_in[4];
    const float* b_ih = (const float*)d_in[5];
    const float* b_hh = (const float*)d_in[6];
    const float* W_a = (const float*)d_in[7];
    const float* b_a = (const float*)d_in[8];
    const float* W_d = (const float*)d_in[9];
    const float* b_d = (const float*)d_in[10];
    float* out = (float*)d_out;

    char* ws = (char*)d_ws;
    unsigned short* xi    = (unsigned short*)(ws + 0);              // 100,663,296 B
    unsigned short* encb  = (unsigned short*)(ws + 100663296);      //  33,554,432 B
    unsigned short* encT  = (unsigned short*)(ws + 134217728);      //  33,554,432 B
    unsigned short* decb  = (unsigned short*)(ws + 167772160);      //  33,554,432 B
    unsigned short* mixb  = (unsigned short*)(ws + 201326592);      //  33,554,432 B
    unsigned short* Wab   = (unsigned short*)(ws + 234881024);      //   1,048,576 B
    unsigned short* Wdb   = (unsigned short*)(ws + 235929600);      //     524,288 B
    unsigned short* hb    = (unsigned short*)(ws + 236453888);      //     131,072 B
    unsigned int*   flags = (unsigned int*)(ws + 236584960);        //      32,768 B

    // zero h double-buffers + flags (ws is re-poisoned 0xAA before every launch)
    hipMemsetAsync(ws + 236453888, 0, 163840, stream);

    k_cvt<<<1024, 256, 0, stream>>>(enc_f, encb, 16777216 / 8);
    k_cvt<<<256, 256, 0, stream>>>(W_a, Wab, 524288 / 8);
    k_cvt<<<128, 256, 0, stream>>>(W_d, Wdb, 262144 / 8);
    k_transpose<<<dim3(64, 8, 8), dim3(64, 4), 0, stream>>>(encb, encT);
    k_gemm_xi<<<dim3(256, 12), 256, 0, stream>>>(emb, W_ih, b_ih, xi);
    k_scan<<<16, 512, 0, stream>>>(W_hh, b_hh, xi, decb, out + 16777216, hb, flags);
    k_attn<<<512, 256, 0, stream>>>(decb, encb, encT, masks, mixb);
    k_out<<<512, 256, 0, stream>>>(mixb, decb, Wab, b_a, Wdb, b_d, out);
}

// Round 4
// 3153.424 us; speedup vs baseline: 1.1879x; 1.1879x over previous
//
#include <hip/hip_runtime.h>

typedef __attribute__((ext_vector_type(8))) short bf16x8;
typedef __attribute__((ext_vector_type(4))) float f32x4;

#define MFMA16(a, b, c) __builtin_amdgcn_mfma_f32_16x16x32_bf16((a), (b), (c), 0, 0, 0)

__device__ __forceinline__ unsigned short f2bf(float f) {
    unsigned int u = __builtin_bit_cast(unsigned int, f);
    u = (u + 0x7fffu + ((u >> 16) & 1u)) >> 16;
    return (unsigned short)u;
}
__device__ __forceinline__ float bf2f(unsigned short s) {
    unsigned int u = ((unsigned int)s) << 16;
    return __builtin_bit_cast(float, u);
}
__device__ __forceinline__ bf16x8 pack8(float4 a, float4 b) {
    bf16x8 v;
    v[0] = (short)f2bf(a.x); v[1] = (short)f2bf(a.y);
    v[2] = (short)f2bf(a.z); v[3] = (short)f2bf(a.w);
    v[4] = (short)f2bf(b.x); v[5] = (short)f2bf(b.y);
    v[6] = (short)f2bf(b.z); v[7] = (short)f2bf(b.w);
    return v;
}
__device__ __forceinline__ float sigmoidf_(float x) { return 1.0f / (1.0f + __expf(-x)); }
__device__ __forceinline__ float tanhf_(float x) { return 2.0f / (1.0f + __expf(-2.0f * x)) - 1.0f; }

// ---------------- elementwise f32 -> bf16 convert ----------------
__global__ void k_cvt(const float* __restrict__ s, unsigned short* __restrict__ d, int n8) {
    int i = blockIdx.x * blockDim.x + threadIdx.x;
    int stride = gridDim.x * blockDim.x;
    for (; i < n8; i += stride) {
        const float4* sp = (const float4*)(s + (size_t)i * 8);
        float4 a = sp[0], b = sp[1];
        *(bf16x8*)(d + (size_t)i * 8) = pack8(a, b);
    }
}

// ---------------- transpose enc [b][s][h] -> [b][h][s] (bf16) ----------------
__global__ void k_transpose(const unsigned short* __restrict__ src, unsigned short* __restrict__ dst) {
    __shared__ unsigned short tile[64][66];
    const int b = blockIdx.x, s0 = blockIdx.y * 64, h0 = blockIdx.z * 64;
    const int tx = threadIdx.x, ty = threadIdx.y;
    for (int r = ty; r < 64; r += 4)
        tile[r][tx] = src[((size_t)(b * 512) + (s0 + r)) * 512 + h0 + tx];
    __syncthreads();
    for (int r = ty; r < 64; r += 4)
        dst[((size_t)(b * 512) + (h0 + r)) * 512 + s0 + tx] = tile[tx][r];
}

// ---------------- K1: xi = emb @ W_ih^T + b_ih  (bf16 out) ----------------
__global__ __launch_bounds__(256) void k_gemm_xi(
    const float* __restrict__ emb, const float* __restrict__ W_ih,
    const float* __restrict__ b_ih, unsigned short* __restrict__ xi) {
    __shared__ unsigned short Asub[2][4096];
    __shared__ unsigned short Bsub[2][4096];
    const int tid = threadIdx.x;
    const int wv = tid >> 6, l = tid & 63, lr = l & 15, lu = l >> 4;
    const int wm = wv >> 1, wn = wv & 1;
    const int row0 = blockIdx.x * 128, col0 = blockIdx.y * 128;

    f32x4 acc[4][4];
#pragma unroll
    for (int mt = 0; mt < 4; ++mt)
#pragma unroll
        for (int nt = 0; nt < 4; ++nt) acc[mt][nt] = (f32x4){0.f, 0.f, 0.f, 0.f};

    bf16x8 sA[2], sB[2];
    auto ldstage = [&](int ks) {
#pragma unroll
        for (int i = 0; i < 2; ++i) {
            int chunk = i * 256 + tid;
            int row = chunk >> 2;
            int ce = (chunk & 3) * 8;
            const float* pa = emb + (size_t)(row0 + row) * 512 + ks * 32 + ce;
            sA[i] = pack8(((const float4*)pa)[0], ((const float4*)pa)[1]);
            const float* pb = W_ih + (size_t)(col0 + row) * 512 + ks * 32 + ce;
            sB[i] = pack8(((const float4*)pb)[0], ((const float4*)pb)[1]);
        }
    };
    auto wrstage = [&](int buf) {
#pragma unroll
        for (int i = 0; i < 2; ++i) {
            int chunk = i * 256 + tid;
            int idx = (chunk & 3) * 1024 + (chunk >> 2) * 8;
            *(bf16x8*)(&Asub[buf][idx]) = sA[i];
            *(bf16x8*)(&Bsub[buf][idx]) = sB[i];
        }
    };
    ldstage(0);
    wrstage(0);
    __syncthreads();
#pragma unroll 1
    for (int ks = 0; ks < 16; ++ks) {
        const int cb = ks & 1;
        if (ks < 15) ldstage(ks + 1);
        bf16x8 af[4];
#pragma unroll
        for (int mt = 0; mt < 4; ++mt)
            af[mt] = *(const bf16x8*)(&Asub[cb][lu * 1024 + (wm * 64 + mt * 16 + lr) * 8]);
#pragma unroll
        for (int nt = 0; nt < 4; ++nt) {
            bf16x8 bb = *(const bf16x8*)(&Bsub[cb][lu * 1024 + (wn * 64 + nt * 16 + lr) * 8]);
#pragma unroll
            for (int mt = 0; mt < 4; ++mt) acc[mt][nt] = MFMA16(af[mt], bb, acc[mt][nt]);
        }
        if (ks < 15) wrstage(cb ^ 1);
        __syncthreads();
    }
#pragma unroll
    for (int nt = 0; nt < 4; ++nt) {
        const int col = col0 + wn * 64 + nt * 16 + lr;
        const float bias = b_ih[col];
#pragma unroll
        for (int mt = 0; mt < 4; ++mt)
#pragma unroll
            for (int j = 0; j < 4; ++j) {
                const int row = row0 + wm * 64 + mt * 16 + lu * 4 + j;
                xi[(size_t)row * 1536 + col] = f2bf(acc[mt][nt][j] + bias);
            }
    }
}

// ---------------- K2: GRU scan. 16 persistent WGs = 4 batch-groups x 4 N-slices. ----------------
// amdgpu_waves_per_eu(2,2): PIN occupancy at 2 waves/EU -> allocator budgets 256 VGPR/wave,
// no incentive to shrink to 128 and rematerialize the 192-reg weight file (round-3 failure).
__global__ __attribute__((amdgpu_flat_work_group_size(512, 512), amdgpu_waves_per_eu(2, 2)))
void k_scan(
    const float* __restrict__ W_hh, const float* __restrict__ b_hh,
    const unsigned short* __restrict__ xi,
    unsigned short* __restrict__ dec, float* __restrict__ hlast,
    unsigned short* hb,            // [4][2][16][512] bf16
    unsigned int* flags) {         // [4][512][4]
    __shared__ unsigned short hlds[16 * 512];    // 16 KB, XOR-swizzled A-tile
    __shared__ unsigned short hstage[16 * 128];  // 4 KB, XOR-swizzled
    const int tid = threadIdx.x;
    const int w = tid >> 6, l = tid & 63, lr = l & 15, lu = l >> 4;
    const int g = blockIdx.x & 3;   // batch group
    const int q = blockIdx.x >> 2;  // N-slice
    const int bg0 = g * 16;
    const int hcol = q * 128 + w * 16 + lr;
    unsigned short* hb_g = hb + g * 16384;
    unsigned int* flag_g = flags + g * 2048;

    // preload W_hh fragments: 3 gates x 16 k-tiles (192 VGPR) -- must stay register-resident
    bf16x8 wf[3][16];
#pragma unroll
    for (int g3 = 0; g3 < 3; ++g3) {
        const float* wr = W_hh + (size_t)(g3 * 512 + hcol) * 512;
#pragma unroll
        for (int kt = 0; kt < 16; ++kt) {
            const float* p = wr + kt * 32 + lu * 8;
            wf[g3][kt] = pack8(*(const float4*)p, *(const float4*)(p + 4));
        }
    }
    float bh[3];
#pragma unroll
    for (int g3 = 0; g3 < 3; ++g3) bh[g3] = b_hh[g3 * 512 + hcol];

    // prefetch xi for t=0
    unsigned short xv[12];
#pragma unroll
    for (int g3 = 0; g3 < 3; ++g3)
#pragma unroll
        for (int j = 0; j < 4; ++j)
            xv[g3 * 4 + j] = xi[((size_t)(bg0 + lu * 4 + j) * 512 + 0) * 1536 + g3 * 512 + hcol];

    float hloc[4] = {0.f, 0.f, 0.f, 0.f};

#pragma clang loop unroll(disable)
    for (int t = 0; t < 512; ++t) {
        // wait for previous step's producers: one poll lane per flag word (low MALL traffic)
        if (t > 0) {
            if (tid < 4) {
                while (__hip_atomic_load(&flag_g[(t - 1) * 4 + tid],
                                         __ATOMIC_RELAXED, __HIP_MEMORY_SCOPE_AGENT) == 0u)
                    __builtin_amdgcn_s_sleep(1);
            }
            __syncthreads();
        }
        // cooperative coherent load of h (16 KB) -> swizzled LDS
        {
            unsigned long long* src = (unsigned long long*)(hb_g + (t & 1) * 8192);
#pragma unroll
            for (int i = 0; i < 4; ++i) {
                int c = i * 512 + tid;
                unsigned long long v = __hip_atomic_load(src + c, __ATOMIC_RELAXED, __HIP_MEMORY_SCOPE_AGENT);
                int row = c >> 7;
                int colb = (c & 127) * 8;
                *(unsigned long long*)((char*)hlds + row * 1024 + (colb ^ ((row & 7) << 4))) = v;
            }
        }
        __syncthreads();
        // MFMA: h[16x512] @ W_slice^T -> 3 gate pre-activations (16x16 tile per wave)
        f32x4 acc0 = (f32x4){0.f, 0.f, 0.f, 0.f};
        f32x4 acc1 = (f32x4){0.f, 0.f, 0.f, 0.f};
        f32x4 acc2 = (f32x4){0.f, 0.f, 0.f, 0.f};
#pragma unroll
        for (int kt = 0; kt < 16; ++kt) {
            bf16x8 a = *(const bf16x8*)((char*)hlds + lr * 1024 + ((kt * 64 + lu * 16) ^ ((lr & 7) << 4)));
            acc0 = MFMA16(a, wf[0][kt], acc0);
            acc1 = MFMA16(a, wf[1][kt], acc1);
            acc2 = MFMA16(a, wf[2][kt], acc2);
        }
        // gates + state update (f32); write h_new to hstage (swizzled)
#pragma unroll
        for (int j = 0; j < 4; ++j) {
            float xr = bf2f(xv[0 * 4 + j]);
            float xz = bf2f(xv[1 * 4 + j]);
            float xn = bf2f(xv[2 * 4 + j]);
            float rr = sigmoidf_(xr + acc0[j] + bh[0]);
            float zz = sigmoidf_(xz + acc1[j] + bh[1]);
            float nn = tanhf_(xn + rr * (acc2[j] + bh[2]));
            float hv = (1.f - zz) * nn + zz * hloc[j];
            hloc[j] = hv;
            int row = lu * 4 + j;
            int colb = (w * 32 + lr * 2) ^ ((row & 7) << 4);
            *(unsigned short*)((char*)hstage + row * 256 + colb) = f2bf(hv);
        }
        // prefetch xi for t+1 (latency hidden by store+sync+spin+load of next step)
        if (t < 511) {
#pragma unroll
            for (int g3 = 0; g3 < 3; ++g3)
#pragma unroll
                for (int j = 0; j < 4; ++j)
                    xv[g3 * 4 + j] = xi[((size_t)(bg0 + lu * 4 + j) * 512 + (t + 1)) * 1536 + g3 * 512 + hcol];
        }
        __syncthreads();
        // cooperative stores: h slice (coherent) + dec (plain)
        {
            int r = tid >> 5, c8 = tid & 31;
            unsigned long long v = *(unsigned long long*)((char*)hstage + r * 256 + ((c8 * 8) ^ ((r & 7) << 4)));
            if (t < 511)
                __hip_atomic_store(
                    (unsigned long long*)(hb_g + ((t + 1) & 1) * 8192 + r * 512 + q * 128) + c8, v,
                    __ATOMIC_RELAXED, __HIP_MEMORY_SCOPE_AGENT);
            *((unsigned long long*)(dec + ((size_t)(bg0 + r) * 512 + t) * 512 + q * 128) + c8) = v;
        }
        __syncthreads();  // drains vmcnt -> all threads' stores complete before flag
        if (t < 511 && tid == 0)
            __hip_atomic_store(&flag_g[t * 4 + q], 1u, __ATOMIC_RELEASE, __HIP_MEMORY_SCOPE_AGENT);
    }
    // final hidden state
#pragma unroll
    for (int j = 0; j < 4; ++j)
        hlast[(size_t)(bg0 + lu * 4 + j) * 512 + hcol] = hloc[j];
}

// ---------------- K3: fused scores + softmax + mix, per (b, 64-row t tile) ----------------
__global__ __launch_bounds__(256) void k_attn(
    const unsigned short* __restrict__ dec, const unsigned short* __restrict__ enc,
    const unsigned short* __restrict__ encT, const unsigned char* __restrict__ masks,
    unsigned short* __restrict__ mix) {
    __shared__ char Pt[65536];
    __shared__ float red[64][4];
    const int tid = threadIdx.x, w = tid >> 6, l = tid & 63, lr = l & 15, lu = l >> 4;
    const int b = blockIdx.x >> 3, t0 = (blockIdx.x & 7) << 6;
    const size_t encBase = (size_t)b * 512 * 512;

    {   // stage dec tile (swizzled)
        const char* src = (const char*)(dec + (size_t)(b * 512 + t0) * 512);
#pragma unroll
        for (int i = 0; i < 16; ++i) {
            int chunk = i * 256 + tid;
            int row = chunk >> 6;
            int colb = (chunk & 63) * 16;
            uint4 v = *(const uint4*)(src + (size_t)row * 1024 + colb);
            *(uint4*)(Pt + row * 1024 + (colb ^ ((row & 7) << 4))) = v;
        }
    }
    __syncthreads();

    f32x4 acc[4][8];
#pragma unroll
    for (int mt = 0; mt < 4; ++mt)
#pragma unroll
        for (int nt = 0; nt < 8; ++nt) acc[mt][nt] = (f32x4){0.f, 0.f, 0.f, 0.f};

#pragma unroll 2
    for (int kt = 0; kt < 16; ++kt) {
        bf16x8 af[4];
#pragma unroll
        for (int mt = 0; mt < 4; ++mt)
            af[mt] = *(const bf16x8*)(Pt + (mt * 16 + lr) * 1024 + ((kt * 64 + lu * 16) ^ ((lr & 7) << 4)));
#pragma unroll
        for (int nt = 0; nt < 8; ++nt) {
            bf16x8 bb = *(const bf16x8*)(enc + encBase + (size_t)(w * 128 + nt * 16 + lr) * 512 + kt * 32 + lu * 8);
#pragma unroll
            for (int mt = 0; mt < 4; ++mt) acc[mt][nt] = MFMA16(af[mt], bb, acc[mt][nt]);
        }
    }
    // mask (True = masked)
#pragma unroll
    for (int nt = 0; nt < 8; ++nt) {
        if (masks[b * 512 + w * 128 + nt * 16 + lr]) {
#pragma unroll
            for (int mt = 0; mt < 4; ++mt)
#pragma unroll
                for (int j = 0; j < 4; ++j) acc[mt][nt][j] = -3.0e38f;
        }
    }
    // softmax over s (512 = 4 waves x 128)
    float rmax[4][4], rinv[4][4];
#pragma unroll
    for (int mt = 0; mt < 4; ++mt)
#pragma unroll
        for (int j = 0; j < 4; ++j) {
            float m = acc[mt][0][j];
#pragma unroll
            for (int nt = 1; nt < 8; ++nt) m = fmaxf(m, acc[mt][nt][j]);
            m = fmaxf(m, __shfl_xor(m, 1));
            m = fmaxf(m, __shfl_xor(m, 2));
            m = fmaxf(m, __shfl_xor(m, 4));
            m = fmaxf(m, __shfl_xor(m, 8));
            if (lr == 0) red[mt * 16 + lu * 4 + j][w] = m;
        }
    __syncthreads();
#pragma unroll
    for (int mt = 0; mt < 4; ++mt)
#pragma unroll
        for (int j = 0; j < 4; ++j) {
            float4 v = *(const float4*)(&red[mt * 16 + lu * 4 + j][0]);
            rmax[mt][j] = fmaxf(fmaxf(v.x, v.y), fmaxf(v.z, v.w));
        }
    __syncthreads();
#pragma unroll
    for (int mt = 0; mt < 4; ++mt)
#pragma unroll
        for (int j = 0; j < 4; ++j) {
            float s = 0.f;
#pragma unroll
            for (int nt = 0; nt < 8; ++nt) {
                float e = __expf(acc[mt][nt][j] - rmax[mt][j]);
                acc[mt][nt][j] = e;
                s += e;
            }
            s += __shfl_xor(s, 1);
            s += __shfl_xor(s, 2);
            s += __shfl_xor(s, 4);
            s += __shfl_xor(s, 8);
            if (lr == 0) red[mt * 16 + lu * 4 + j][w] = s;
        }
    __syncthreads();
#pragma unroll
    for (int mt = 0; mt < 4; ++mt)
#pragma unroll
        for (int j = 0; j < 4; ++j) {
            float4 v = *(const float4*)(&red[mt * 16 + lu * 4 + j][0]);
            rinv[mt][j] = 1.f / (v.x + v.y + v.z + v.w);
        }
    // write P (bf16) into Pt (swizzled)
#pragma unroll
    for (int mt = 0; mt < 4; ++mt)
#pragma unroll
        for (int nt = 0; nt < 8; ++nt)
#pragma unroll
            for (int j = 0; j < 4; ++j) {
                int row = mt * 16 + lu * 4 + j;
                int colb = (w * 128 + nt * 16 + lr) * 2;
                *(unsigned short*)(Pt + row * 1024 + (colb ^ ((row & 7) << 4))) =
                    f2bf(acc[mt][nt][j] * rinv[mt][j]);
            }
    __syncthreads();
    // mix = P @ enc  (B from encT, B^T layout)
#pragma unroll
    for (int mt = 0; mt < 4; ++mt)
#pragma unroll
        for (int nt = 0; nt < 8; ++nt) acc[mt][nt] = (f32x4){0.f, 0.f, 0.f, 0.f};
#pragma unroll 2
    for (int kt = 0; kt < 16; ++kt) {
        bf16x8 af[4];
#pragma unroll
        for (int mt = 0; mt < 4; ++mt)
            af[mt] = *(const bf16x8*)(Pt + (mt * 16 + lr) * 1024 + ((kt * 64 + lu * 16) ^ ((lr & 7) << 4)));
#pragma unroll
        for (int nt = 0; nt < 8; ++nt) {
            bf16x8 bb = *(const bf16x8*)(encT + encBase + (size_t)(w * 128 + nt * 16 + lr) * 512 + kt * 32 + lu * 8);
#pragma unroll
            for (int mt = 0; mt < 4; ++mt) acc[mt][nt] = MFMA16(af[mt], bb, acc[mt][nt]);
        }
    }
#pragma unroll
    for (int mt = 0; mt < 4; ++mt)
#pragma unroll
        for (int nt = 0; nt < 8; ++nt)
#pragma unroll
            for (int j = 0; j < 4; ++j) {
                int row = mt * 16 + lu * 4 + j, col = w * 128 + nt * 16 + lr;
                mix[(size_t)(b * 512 + t0 + row) * 512 + col] = f2bf(acc[mt][nt][j]);
            }
}

// ---------------- K4: out = tanh([mix,dec] @ Wa^T + ba) @ Wd^T + bd ----------------
__global__ __launch_bounds__(256) void k_out(
    const unsigned short* __restrict__ mix, const unsigned short* __restrict__ dec,
    const unsigned short* __restrict__ Wa, const float* __restrict__ ba,
    const unsigned short* __restrict__ Wd, const float* __restrict__ bd,
    float* __restrict__ out) {
    __shared__ char At[65536];
    const int tid = threadIdx.x, w = tid >> 6, l = tid & 63, lr = l & 15, lu = l >> 4;
    const int b = blockIdx.x >> 3, t0 = (blockIdx.x & 7) << 6;

    f32x4 acc[4][8];
#pragma unroll
    for (int mt = 0; mt < 4; ++mt)
#pragma unroll
        for (int nt = 0; nt < 8; ++nt) acc[mt][nt] = (f32x4){0.f, 0.f, 0.f, 0.f};

#pragma unroll 1
    for (int half = 0; half < 2; ++half) {
        const unsigned short* srcp = half ? dec : mix;
        const char* src = (const char*)(srcp + (size_t)(b * 512 + t0) * 512);
#pragma unroll
        for (int i = 0; i < 16; ++i) {
            int chunk = i * 256 + tid;
            int row = chunk >> 6;
            int colb = (chunk & 63) * 16;
            uint4 v = *(const uint4*)(src + (size_t)row * 1024 + colb);
            *(uint4*)(At + row * 1024 + (colb ^ ((row & 7) << 4))) = v;
        }
        __syncthreads();
#pragma unroll 2
        for (int kt = 0; kt < 16; ++kt) {
            bf16x8 af[4];
#pragma unroll
            for (int mt = 0; mt < 4; ++mt)
                af[mt] = *(const bf16x8*)(At + (mt * 16 + lr) * 1024 + ((kt * 64 + lu * 16) ^ ((lr & 7) << 4)));
#pragma unroll
            for (int nt = 0; nt < 8; ++nt) {
                bf16x8 bb = *(const bf16x8*)(Wa + (size_t)(w * 128 + nt * 16 + lr) * 1024 + half * 512 + kt * 32 + lu * 8);
#pragma unroll
                for (int mt = 0; mt < 4; ++mt) acc[mt][nt] = MFMA16(af[mt], bb, acc[mt][nt]);
            }
        }
        __syncthreads();
    }
    // tanh epilogue -> bf16 into At
    float bav[8];
#pragma unroll
    for (int nt = 0; nt < 8; ++nt) bav[nt] = ba[w * 128 + nt * 16 + lr];
#pragma unroll
    for (int mt = 0; mt < 4; ++mt)
#pragma unroll
        for (int nt = 0; nt < 8; ++nt)
#pragma unroll
            for (int j = 0; j < 4; ++j) {
                float v = tanhf_(acc[mt][nt][j] + bav[nt]);
                int row = mt * 16 + lu * 4 + j;
                int colb = (w * 128 + nt * 16 + lr) * 2;
                *(unsigned short*)(At + row * 1024 + (colb ^ ((row & 7) << 4))) = f2bf(v);
            }
    __syncthreads();
    // dense
#pragma unroll
    for (int mt = 0; mt < 4; ++mt)
#pragma unroll
        for (int nt = 0; nt < 8; ++nt) acc[mt][nt] = (f32x4){0.f, 0.f, 0.f, 0.f};
#pragma unroll 2
    for (int kt = 0; kt < 16; ++kt) {
        bf16x8 af[4];
#pragma unroll
        for (int mt = 0; mt < 4; ++mt)
            af[mt] = *(const bf16x8*)(At + (mt * 16 + lr) * 1024 + ((kt * 64 + lu * 16) ^ ((lr & 7) << 4)));
#pragma unroll
        for (int nt = 0; nt < 8; ++nt) {
            bf16x8 bb = *(const bf16x8*)(Wd + (size_t)(w * 128 + nt * 16 + lr) * 512 + kt * 32 + lu * 8);
#pragma unroll
            for (int mt = 0; mt < 4; ++mt) acc[mt][nt] = MFMA16(af[mt], bb, acc[mt][nt]);
        }
    }
#pragma unroll
    for (int nt = 0; nt < 8; ++nt) {
        const int col = w * 128 + nt * 16 + lr;
        const float bdv = bd[col];
#pragma unroll
        for (int mt = 0; mt < 4; ++mt)
#pragma unroll
            for (int j = 0; j < 4; ++j) {
                int row = mt * 16 + lu * 4 + j;
                out[(size_t)(b * 512 + t0 + row) * 512 + col] = acc[mt][nt][j] + bdv;
            }
    }
}

extern "C" void kernel_launch(void* const* d_in, const int* in_sizes, int n_in,
                              void* d_out, int out_size, void* d_ws, size_t ws_size,
                              hipStream_t stream) {
    const float* emb = (const float*)d_in[0];
    const float* enc_f = (const float*)d_in[1];
    const unsigned char* masks = (const unsigned char*)d_in[2];
    const float* W_ih = (const float*)d_in[3];
    const float* W_hh = (const float*)d_in[4];
    const float* b_ih = (const float*)d_in[5];
    const float* b_hh = (const float*)d_in[6];
    const float* W_a = (const float*)d_in[7];
    const float* b_a = (const float*)d_in[8];
    const float* W_d = (const float*)d_in[9];
    const float* b_d = (const float*)d_in[10];
    float* out = (float*)d_out;

    char* ws = (char*)d_ws;
    unsigned short* xi    = (unsigned short*)(ws + 0);              // 100,663,296 B
    unsigned short* encb  = (unsigned short*)(ws + 100663296);      //  33,554,432 B
    unsigned short* encT  = (unsigned short*)(ws + 134217728);      //  33,554,432 B
    unsigned short* decb  = (unsigned short*)(ws + 167772160);      //  33,554,432 B
    unsigned short* mixb  = (unsigned short*)(ws + 201326592);      //  33,554,432 B
    unsigned short* Wab   = (unsigned short*)(ws + 234881024);      //   1,048,576 B
    unsigned short* Wdb   = (unsigned short*)(ws + 235929600);      //     524,288 B
    unsigned short* hb    = (unsigned short*)(ws + 236453888);      //     131,072 B
    unsigned int*   flags = (unsigned int*)(ws + 236584960);        //      32,768 B

    // zero h double-buffers + flags (ws is re-poisoned 0xAA before every launch)
    hipMemsetAsync(ws + 236453888, 0, 163840, stream);

    k_cvt<<<1024, 256, 0, stream>>>(enc_f, encb, 16777216 / 8);
    k_cvt<<<256, 256, 0, stream>>>(W_a, Wab, 524288 / 8);
    k_cvt<<<128, 256, 0, stream>>>(W_d, Wdb, 262144 / 8);
    k_transpose<<<dim3(64, 8, 8), dim3(64, 4), 0, stream>>>(encb, encT);
    k_gemm_xi<<<dim3(256, 12), 256, 0, stream>>>(emb, W_ih, b_ih, xi);
    k_scan<<<16, 512, 0, stream>>>(W_hh, b_hh, xi, decb, out + 16777216, hb, flags);
    k_attn<<<512, 256, 0, stream>>>(decb, encb, encT, masks, mixb);
    k_out<<<512, 256, 0, stream>>>(mixb, decb, Wab, b_a, Wdb, b_d, out);
}

// Round 6
// 2784.545 us; speedup vs baseline: 1.3453x; 1.1325x over previous
//
#include <hip/hip_runtime.h>

typedef __attribute__((ext_vector_type(8))) short bf16x8;
typedef __attribute__((ext_vector_type(4))) float f32x4;
typedef unsigned long long u64;

#define MFMA16(a, b, c) __builtin_amdgcn_mfma_f32_16x16x32_bf16((a), (b), (c), 0, 0, 0)

__device__ __forceinline__ unsigned short f2bf(float f) {
    unsigned int u = __builtin_bit_cast(unsigned int, f);
    u = (u + 0x7fffu + ((u >> 16) & 1u)) >> 16;
    return (unsigned short)u;
}
__device__ __forceinline__ float bf2f(unsigned short s) {
    unsigned int u = ((unsigned int)s) << 16;
    return __builtin_bit_cast(float, u);
}
__device__ __forceinline__ bf16x8 pack8(float4 a, float4 b) {
    bf16x8 v;
    v[0] = (short)f2bf(a.x); v[1] = (short)f2bf(a.y);
    v[2] = (short)f2bf(a.z); v[3] = (short)f2bf(a.w);
    v[4] = (short)f2bf(b.x); v[5] = (short)f2bf(b.y);
    v[6] = (short)f2bf(b.z); v[7] = (short)f2bf(b.w);
    return v;
}
__device__ __forceinline__ float sigmoidf_(float x) { return 1.0f / (1.0f + __expf(-x)); }
__device__ __forceinline__ float tanhf_(float x) { return 2.0f / (1.0f + __expf(-2.0f * x)) - 1.0f; }

// ---------------- elementwise f32 -> bf16 convert ----------------
__global__ void k_cvt(const float* __restrict__ s, unsigned short* __restrict__ d, int n8) {
    int i = blockIdx.x * blockDim.x + threadIdx.x;
    int stride = gridDim.x * blockDim.x;
    for (; i < n8; i += stride) {
        const float4* sp = (const float4*)(s + (size_t)i * 8);
        float4 a = sp[0], b = sp[1];
        *(bf16x8*)(d + (size_t)i * 8) = pack8(a, b);
    }
}

// ---------------- transpose enc [b][s][h] -> [b][h][s] (bf16) ----------------
__global__ void k_transpose(const unsigned short* __restrict__ src, unsigned short* __restrict__ dst) {
    __shared__ unsigned short tile[64][66];
    const int b = blockIdx.x, s0 = blockIdx.y * 64, h0 = blockIdx.z * 64;
    const int tx = threadIdx.x, ty = threadIdx.y;
    for (int r = ty; r < 64; r += 4)
        tile[r][tx] = src[((size_t)(b * 512) + (s0 + r)) * 512 + h0 + tx];
    __syncthreads();
    for (int r = ty; r < 64; r += 4)
        dst[((size_t)(b * 512) + (h0 + r)) * 512 + s0 + tx] = tile[tx][r];
}

// ---------------- K1: xi = emb @ W_ih^T + b_ih  (bf16 out) ----------------
__global__ __launch_bounds__(256) void k_gemm_xi(
    const float* __restrict__ emb, const float* __restrict__ W_ih,
    const float* __restrict__ b_ih, unsigned short* __restrict__ xi) {
    __shared__ unsigned short Asub[2][4096];
    __shared__ unsigned short Bsub[2][4096];
    const int tid = threadIdx.x;
    const int wv = tid >> 6, l = tid & 63, lr = l & 15, lu = l >> 4;
    const int wm = wv >> 1, wn = wv & 1;
    const int row0 = blockIdx.x * 128, col0 = blockIdx.y * 128;

    f32x4 acc[4][4];
#pragma unroll
    for (int mt = 0; mt < 4; ++mt)
#pragma unroll
        for (int nt = 0; nt < 4; ++nt) acc[mt][nt] = (f32x4){0.f, 0.f, 0.f, 0.f};

    bf16x8 sA[2], sB[2];
    auto ldstage = [&](int ks) {
#pragma unroll
        for (int i = 0; i < 2; ++i) {
            int chunk = i * 256 + tid;
            int row = chunk >> 2;
            int ce = (chunk & 3) * 8;
            const float* pa = emb + (size_t)(row0 + row) * 512 + ks * 32 + ce;
            sA[i] = pack8(((const float4*)pa)[0], ((const float4*)pa)[1]);
            const float* pb = W_ih + (size_t)(col0 + row) * 512 + ks * 32 + ce;
            sB[i] = pack8(((const float4*)pb)[0], ((const float4*)pb)[1]);
        }
    };
    auto wrstage = [&](int buf) {
#pragma unroll
        for (int i = 0; i < 2; ++i) {
            int chunk = i * 256 + tid;
            int idx = (chunk & 3) * 1024 + (chunk >> 2) * 8;
            *(bf16x8*)(&Asub[buf][idx]) = sA[i];
            *(bf16x8*)(&Bsub[buf][idx]) = sB[i];
        }
    };
    ldstage(0);
    wrstage(0);
    __syncthreads();
#pragma unroll 1
    for (int ks = 0; ks < 16; ++ks) {
        const int cb = ks & 1;
        if (ks < 15) ldstage(ks + 1);
        bf16x8 af[4];
#pragma unroll
        for (int mt = 0; mt < 4; ++mt)
            af[mt] = *(const bf16x8*)(&Asub[cb][lu * 1024 + (wm * 64 + mt * 16 + lr) * 8]);
#pragma unroll
        for (int nt = 0; nt < 4; ++nt) {
            bf16x8 bb = *(const bf16x8*)(&Bsub[cb][lu * 1024 + (wn * 64 + nt * 16 + lr) * 8]);
#pragma unroll
            for (int mt = 0; mt < 4; ++mt) acc[mt][nt] = MFMA16(af[mt], bb, acc[mt][nt]);
        }
        if (ks < 15) wrstage(cb ^ 1);
        __syncthreads();
    }
#pragma unroll
    for (int nt = 0; nt < 4; ++nt) {
        const int col = col0 + wn * 64 + nt * 16 + lr;
        const float bias = b_ih[col];
#pragma unroll
        for (int mt = 0; mt < 4; ++mt)
#pragma unroll
            for (int j = 0; j < 4; ++j) {
                const int row = row0 + wm * 64 + mt * 16 + lu * 4 + j;
                xi[(size_t)row * 1536 + col] = f2bf(acc[mt][nt][j] + bias);
            }
    }
}

// ---------------- K2: GRU scan. 32 persistent WGs = 4 batch-groups x 8 col-slices(64). ----------
// 1024 threads = 16 waves = (ct in [0,4)) x (ks in [0,4)). Per wave: 3 gates x 4 K-tiles
// = 48 VGPR of weights -> fits the compiler's 128-reg budget, NO remat (r3/r4 failure mode).
// Partial gate sums combined across ks via LDS; waves 0-3 do gates; waves 4-7 do stores.
__global__ __launch_bounds__(1024) void k_scan(
    const float* __restrict__ W_hh, const float* __restrict__ b_hh,
    const unsigned short* __restrict__ xi,
    unsigned short* __restrict__ dec, float* __restrict__ hlast,
    unsigned short* hb,            // [4][2][16][512] bf16
    unsigned int* flags) {         // [4][512][8]
    __shared__ unsigned short hlds[16 * 512];   // 16 KB, XOR-swizzled A-tile
    __shared__ f32x4 gacc[3][4][4][64];         // 48 KB partial gate sums [g3][ks][ct][lane]
    __shared__ unsigned short hstage[16 * 64];  // 2 KB, XOR-swizzled h_new slice
    const int tid = threadIdx.x;
    const int w = tid >> 6, l = tid & 63, lr = l & 15, lu = l >> 4;
    const int ct = w & 3, ks = w >> 2;
    const int g = blockIdx.x & 3;   // batch group
    const int q = blockIdx.x >> 2;  // 64-col slice in [0,8)
    const int bg0 = g * 16;
    const int col = q * 64 + ct * 16 + lr;  // this wave's output column
    unsigned short* hb_g = hb + g * 16384;
    unsigned int* flag_g = flags + g * 4096;

    // weights: 3 gates x 4 K-tiles (kt_global = ks*4+kk)  -> 48 VGPR, loop-invariant
    bf16x8 wf[3][4];
#pragma unroll
    for (int g3 = 0; g3 < 3; ++g3) {
        const float* wr = W_hh + (size_t)(g3 * 512 + col) * 512;
#pragma unroll
        for (int kk = 0; kk < 4; ++kk) {
            const float* p = wr + (ks * 4 + kk) * 32 + lu * 8;
            wf[g3][kk] = pack8(*(const float4*)p, *(const float4*)(p + 4));
        }
    }

    // combine-wave state (waves 0-3 only)
    float bh[3] = {0.f, 0.f, 0.f};
    unsigned short xv[12];
    float hloc[4] = {0.f, 0.f, 0.f, 0.f};
    if (w < 4) {
#pragma unroll
        for (int g3 = 0; g3 < 3; ++g3) bh[g3] = b_hh[g3 * 512 + col];
#pragma unroll
        for (int g3 = 0; g3 < 3; ++g3)
#pragma unroll
            for (int j = 0; j < 4; ++j)
                xv[g3 * 4 + j] = xi[((size_t)(bg0 + lu * 4 + j) * 512) * 1536 + g3 * 512 + col];
    }

#pragma clang loop unroll(disable)
    for (int t = 0; t < 512; ++t) {
        // 1. wait for previous step's 8 producers (one poll lane per flag word)
        if (t > 0) {
            if (tid < 8) {
                while (__hip_atomic_load(&flag_g[(t - 1) * 8 + tid],
                                         __ATOMIC_RELAXED, __HIP_MEMORY_SCOPE_AGENT) == 0u)
                    __builtin_amdgcn_s_sleep(1);
            }
            __syncthreads();
        }
        // 2. cooperative coherent load of h(t) (16 KB) -> swizzled LDS
        {
            const u64* src = (const u64*)(hb_g + (t & 1) * 8192);
#pragma unroll
            for (int i = 0; i < 2; ++i) {
                int c = i * 1024 + tid;
                u64 v = __hip_atomic_load(src + c, __ATOMIC_RELAXED, __HIP_MEMORY_SCOPE_AGENT);
                int row = c >> 7;
                int colb = (c & 127) * 8;
                *(u64*)((char*)hlds + row * 1024 + (colb ^ ((row & 7) << 4))) = v;
            }
        }
        __syncthreads();
        // 3. MFMA: partial gate pre-activations over this wave's K-quarter
        f32x4 a0 = (f32x4){0.f, 0.f, 0.f, 0.f};
        f32x4 a1 = (f32x4){0.f, 0.f, 0.f, 0.f};
        f32x4 a2 = (f32x4){0.f, 0.f, 0.f, 0.f};
#pragma unroll
        for (int kk = 0; kk < 4; ++kk) {
            const int kt = ks * 4 + kk;
            bf16x8 a = *(const bf16x8*)((char*)hlds + lr * 1024 + ((kt * 64 + lu * 16) ^ ((lr & 7) << 4)));
            a0 = MFMA16(a, wf[0][kk], a0);
            a1 = MFMA16(a, wf[1][kk], a1);
            a2 = MFMA16(a, wf[2][kk], a2);
        }
        gacc[0][ks][ct][l] = a0;
        gacc[1][ks][ct][l] = a1;
        gacc[2][ks][ct][l] = a2;
        __syncthreads();
        // 4. combine (waves 0-3): sum K-quarters, gates, h update, stage h_new
        if (w < 4) {
            f32x4 s0 = gacc[0][0][ct][l];
            f32x4 s1 = gacc[1][0][ct][l];
            f32x4 s2 = gacc[2][0][ct][l];
#pragma unroll
            for (int k2 = 1; k2 < 4; ++k2) {
                s0 += gacc[0][k2][ct][l];
                s1 += gacc[1][k2][ct][l];
                s2 += gacc[2][k2][ct][l];
            }
#pragma unroll
            for (int j = 0; j < 4; ++j) {
                float xr = bf2f(xv[0 * 4 + j]);
                float xz = bf2f(xv[1 * 4 + j]);
                float xn = bf2f(xv[2 * 4 + j]);
                float rr = sigmoidf_(xr + s0[j] + bh[0]);
                float zz = sigmoidf_(xz + s1[j] + bh[1]);
                float nn = tanhf_(xn + rr * (s2[j] + bh[2]));
                float hv = (1.f - zz) * nn + zz * hloc[j];
                hloc[j] = hv;
                int batch = lu * 4 + j;
                int cw = ct * 16 + lr;
                hstage[batch * 64 + (cw ^ ((batch & 7) << 3))] = f2bf(hv);
            }
            // prefetch xi(t+1) (overlaps store phase)
            if (t < 511) {
#pragma unroll
                for (int g3 = 0; g3 < 3; ++g3)
#pragma unroll
                    for (int j = 0; j < 4; ++j)
                        xv[g3 * 4 + j] =
                            xi[((size_t)(bg0 + lu * 4 + j) * 512 + (t + 1)) * 1536 + g3 * 512 + col];
            }
        }
        __syncthreads();
        // 5. stores (waves 4-7): h slice (coherent) + dec (plain), 2 KB each
        if (w >= 4 && w < 8) {
            int i = tid - 256;             // [0,256)
            int batch = i >> 4, w8 = i & 15;
            u64 v = ((const u64*)hstage)[batch * 16 + (w8 ^ ((batch & 7) << 1))];
            if (t < 511)
                __hip_atomic_store(
                    (u64*)(hb_g + ((t + 1) & 1) * 8192 + batch * 512 + q * 64) + w8, v,
                    __ATOMIC_RELAXED, __HIP_MEMORY_SCOPE_AGENT);
            *((u64*)(dec + ((size_t)(bg0 + batch) * 512 + t) * 512 + q * 64) + w8) = v;
        }
        __syncthreads();  // per-wave vmcnt(0) drain before barrier -> stores globally visible
        if (t < 511 && tid == 0)
            __hip_atomic_store(&flag_g[t * 8 + q], 1u, __ATOMIC_RELEASE, __HIP_MEMORY_SCOPE_AGENT);
    }
    // final hidden state from register carry (waves 0-3)
    if (w < 4) {
#pragma unroll
        for (int j = 0; j < 4; ++j)
            hlast[(size_t)(bg0 + lu * 4 + j) * 512 + col] = hloc[j];
    }
}

// ---------------- K3: fused scores + softmax + mix, per (b, 64-row t tile) ----------------
__global__ __launch_bounds__(256) void k_attn(
    const unsigned short* __restrict__ dec, const unsigned short* __restrict__ enc,
    const unsigned short* __restrict__ encT, const unsigned char* __restrict__ masks,
    unsigned short* __restrict__ mix) {
    __shared__ char Pt[65536];
    __shared__ float red[64][4];
    const int tid = threadIdx.x, w = tid >> 6, l = tid & 63, lr = l & 15, lu = l >> 4;
    const int b = blockIdx.x >> 3, t0 = (blockIdx.x & 7) << 6;
    const size_t encBase = (size_t)b * 512 * 512;

    {   // stage dec tile (swizzled)
        const char* src = (const char*)(dec + (size_t)(b * 512 + t0) * 512);
#pragma unroll
        for (int i = 0; i < 16; ++i) {
            int chunk = i * 256 + tid;
            int row = chunk >> 6;
            int colb = (chunk & 63) * 16;
            uint4 v = *(const uint4*)(src + (size_t)row * 1024 + colb);
            *(uint4*)(Pt + row * 1024 + (colb ^ ((row & 7) << 4))) = v;
        }
    }
    __syncthreads();

    f32x4 acc[4][8];
#pragma unroll
    for (int mt = 0; mt < 4; ++mt)
#pragma unroll
        for (int nt = 0; nt < 8; ++nt) acc[mt][nt] = (f32x4){0.f, 0.f, 0.f, 0.f};

#pragma unroll 2
    for (int kt = 0; kt < 16; ++kt) {
        bf16x8 af[4];
#pragma unroll
        for (int mt = 0; mt < 4; ++mt)
            af[mt] = *(const bf16x8*)(Pt + (mt * 16 + lr) * 1024 + ((kt * 64 + lu * 16) ^ ((lr & 7) << 4)));
#pragma unroll
        for (int nt = 0; nt < 8; ++nt) {
            bf16x8 bb = *(const bf16x8*)(enc + encBase + (size_t)(w * 128 + nt * 16 + lr) * 512 + kt * 32 + lu * 8);
#pragma unroll
            for (int mt = 0; mt < 4; ++mt) acc[mt][nt] = MFMA16(af[mt], bb, acc[mt][nt]);
        }
    }
    // mask (True = masked)
#pragma unroll
    for (int nt = 0; nt < 8; ++nt) {
        if (masks[b * 512 + w * 128 + nt * 16 + lr]) {
#pragma unroll
            for (int mt = 0; mt < 4; ++mt)
#pragma unroll
                for (int j = 0; j < 4; ++j) acc[mt][nt][j] = -3.0e38f;
        }
    }
    // softmax over s (512 = 4 waves x 128)
    float rmax[4][4], rinv[4][4];
#pragma unroll
    for (int mt = 0; mt < 4; ++mt)
#pragma unroll
        for (int j = 0; j < 4; ++j) {
            float m = acc[mt][0][j];
#pragma unroll
            for (int nt = 1; nt < 8; ++nt) m = fmaxf(m, acc[mt][nt][j]);
            m = fmaxf(m, __shfl_xor(m, 1));
            m = fmaxf(m, __shfl_xor(m, 2));
            m = fmaxf(m, __shfl_xor(m, 4));
            m = fmaxf(m, __shfl_xor(m, 8));
            if (lr == 0) red[mt * 16 + lu * 4 + j][w] = m;
        }
    __syncthreads();
#pragma unroll
    for (int mt = 0; mt < 4; ++mt)
#pragma unroll
        for (int j = 0; j < 4; ++j) {
            float4 v = *(const float4*)(&red[mt * 16 + lu * 4 + j][0]);
            rmax[mt][j] = fmaxf(fmaxf(v.x, v.y), fmaxf(v.z, v.w));
        }
    __syncthreads();
#pragma unroll
    for (int mt = 0; mt < 4; ++mt)
#pragma unroll
        for (int j = 0; j < 4; ++j) {
            float s = 0.f;
#pragma unroll
            for (int nt = 0; nt < 8; ++nt) {
                float e = __expf(acc[mt][nt][j] - rmax[mt][j]);
                acc[mt][nt][j] = e;
                s += e;
            }
            s += __shfl_xor(s, 1);
            s += __shfl_xor(s, 2);
            s += __shfl_xor(s, 4);
            s += __shfl_xor(s, 8);
            if (lr == 0) red[mt * 16 + lu * 4 + j][w] = s;
        }
    __syncthreads();
#pragma unroll
    for (int mt = 0; mt < 4; ++mt)
#pragma unroll
        for (int j = 0; j < 4; ++j) {
            float4 v = *(const float4*)(&red[mt * 16 + lu * 4 + j][0]);
            rinv[mt][j] = 1.f / (v.x + v.y + v.z + v.w);
        }
    // write P (bf16) into Pt (swizzled)
#pragma unroll
    for (int mt = 0; mt < 4; ++mt)
#pragma unroll
        for (int nt = 0; nt < 8; ++nt)
#pragma unroll
            for (int j = 0; j < 4; ++j) {
                int row = mt * 16 + lu * 4 + j;
                int colb = (w * 128 + nt * 16 + lr) * 2;
                *(unsigned short*)(Pt + row * 1024 + (colb ^ ((row & 7) << 4))) =
                    f2bf(acc[mt][nt][j] * rinv[mt][j]);
            }
    __syncthreads();
    // mix = P @ enc  (B from encT, B^T layout)
#pragma unroll
    for (int mt = 0; mt < 4; ++mt)
#pragma unroll
        for (int nt = 0; nt < 8; ++nt) acc[mt][nt] = (f32x4){0.f, 0.f, 0.f, 0.f};
#pragma unroll 2
    for (int kt = 0; kt < 16; ++kt) {
        bf16x8 af[4];
#pragma unroll
        for (int mt = 0; mt < 4; ++mt)
            af[mt] = *(const bf16x8*)(Pt + (mt * 16 + lr) * 1024 + ((kt * 64 + lu * 16) ^ ((lr & 7) << 4)));
#pragma unroll
        for (int nt = 0; nt < 8; ++nt) {
            bf16x8 bb = *(const bf16x8*)(encT + encBase + (size_t)(w * 128 + nt * 16 + lr) * 512 + kt * 32 + lu * 8);
#pragma unroll
            for (int mt = 0; mt < 4; ++mt) acc[mt][nt] = MFMA16(af[mt], bb, acc[mt][nt]);
        }
    }
#pragma unroll
    for (int mt = 0; mt < 4; ++mt)
#pragma unroll
        for (int nt = 0; nt < 8; ++nt)
#pragma unroll
            for (int j = 0; j < 4; ++j) {
                int row = mt * 16 + lu * 4 + j, col = w * 128 + nt * 16 + lr;
                mix[(size_t)(b * 512 + t0 + row) * 512 + col] = f2bf(acc[mt][nt][j]);
            }
}

// ---------------- K4: out = tanh([mix,dec] @ Wa^T + ba) @ Wd^T + bd ----------------
__global__ __launch_bounds__(256) void k_out(
    const unsigned short* __restrict__ mix, const unsigned short* __restrict__ dec,
    const unsigned short* __restrict__ Wa, const float* __restrict__ ba,
    const unsigned short* __restrict__ Wd, const float* __restrict__ bd,
    float* __restrict__ out) {
    __shared__ char At[65536];
    const int tid = threadIdx.x, w = tid >> 6, l = tid & 63, lr = l & 15, lu = l >> 4;
    const int b = blockIdx.x >> 3, t0 = (blockIdx.x & 7) << 6;

    f32x4 acc[4][8];
#pragma unroll
    for (int mt = 0; mt < 4; ++mt)
#pragma unroll
        for (int nt = 0; nt < 8; ++nt) acc[mt][nt] = (f32x4){0.f, 0.f, 0.f, 0.f};

#pragma unroll 1
    for (int half = 0; half < 2; ++half) {
        const unsigned short* srcp = half ? dec : mix;
        const char* src = (const char*)(srcp + (size_t)(b * 512 + t0) * 512);
#pragma unroll
        for (int i = 0; i < 16; ++i) {
            int chunk = i * 256 + tid;
            int row = chunk >> 6;
            int colb = (chunk & 63) * 16;
            uint4 v = *(const uint4*)(src + (size_t)row * 1024 + colb);
            *(uint4*)(At + row * 1024 + (colb ^ ((row & 7) << 4))) = v;
        }
        __syncthreads();
#pragma unroll 2
        for (int kt = 0; kt < 16; ++kt) {
            bf16x8 af[4];
#pragma unroll
            for (int mt = 0; mt < 4; ++mt)
                af[mt] = *(const bf16x8*)(At + (mt * 16 + lr) * 1024 + ((kt * 64 + lu * 16) ^ ((lr & 7) << 4)));
#pragma unroll
            for (int nt = 0; nt < 8; ++nt) {
                bf16x8 bb = *(const bf16x8*)(Wa + (size_t)(w * 128 + nt * 16 + lr) * 1024 + half * 512 + kt * 32 + lu * 8);
#pragma unroll
                for (int mt = 0; mt < 4; ++mt) acc[mt][nt] = MFMA16(af[mt], bb, acc[mt][nt]);
            }
        }
        __syncthreads();
    }
    // tanh epilogue -> bf16 into At
    float bav[8];
#pragma unroll
    for (int nt = 0; nt < 8; ++nt) bav[nt] = ba[w * 128 + nt * 16 + lr];
#pragma unroll
    for (int mt = 0; mt < 4; ++mt)
#pragma unroll
        for (int nt = 0; nt < 8; ++nt)
#pragma unroll
            for (int j = 0; j < 4; ++j) {
                float v = tanhf_(acc[mt][nt][j] + bav[nt]);
                int row = mt * 16 + lu * 4 + j;
                int colb = (w * 128 + nt * 16 + lr) * 2;
                *(unsigned short*)(At + row * 1024 + (colb ^ ((row & 7) << 4))) = f2bf(v);
            }
    __syncthreads();
    // dense
#pragma unroll
    for (int mt = 0; mt < 4; ++mt)
#pragma unroll
        for (int nt = 0; nt < 8; ++nt) acc[mt][nt] = (f32x4){0.f, 0.f, 0.f, 0.f};
#pragma unroll 2
    for (int kt = 0; kt < 16; ++kt) {
        bf16x8 af[4];
#pragma unroll
        for (int mt = 0; mt < 4; ++mt)
            af[mt] = *(const bf16x8*)(At + (mt * 16 + lr) * 1024 + ((kt * 64 + lu * 16) ^ ((lr & 7) << 4)));
#pragma unroll
        for (int nt = 0; nt < 8; ++nt) {
            bf16x8 bb = *(const bf16x8*)(Wd + (size_t)(w * 128 + nt * 16 + lr) * 512 + kt * 32 + lu * 8);
#pragma unroll
            for (int mt = 0; mt < 4; ++mt) acc[mt][nt] = MFMA16(af[mt], bb, acc[mt][nt]);
        }
    }
#pragma unroll
    for (int nt = 0; nt < 8; ++nt) {
        const int col = w * 128 + nt * 16 + lr;
        const float bdv = bd[col];
#pragma unroll
        for (int mt = 0; mt < 4; ++mt)
#pragma unroll
            for (int j = 0; j < 4; ++j) {
                int row = mt * 16 + lu * 4 + j;
                out[(size_t)(b * 512 + t0 + row) * 512 + col] = acc[mt][nt][j] + bdv;
            }
    }
}

extern "C" void kernel_launch(void* const* d_in, const int* in_sizes, int n_in,
                              void* d_out, int out_size, void* d_ws, size_t ws_size,
                              hipStream_t stream) {
    const float* emb = (const float*)d_in[0];
    const float* enc_f = (const float*)d_in[1];
    const unsigned char* masks = (const unsigned char*)d_in[2];
    const float* W_ih = (const float*)d_in[3];
    const float* W_hh = (const float*)d_in[4];
    const float* b_ih = (const float*)d_in[5];
    const float* b_hh = (const float*)d_in[6];
    const float* W_a = (const float*)d_in[7];
    const float* b_a = (const float*)d_in[8];
    const float* W_d = (const float*)d_in[9];
    const float* b_d = (const float*)d_in[10];
    float* out = (float*)d_out;

    char* ws = (char*)d_ws;
    unsigned short* xi    = (unsigned short*)(ws + 0);              // 100,663,296 B
    unsigned short* encb  = (unsigned short*)(ws + 100663296);      //  33,554,432 B
    unsigned short* encT  = (unsigned short*)(ws + 134217728);      //  33,554,432 B
    unsigned short* decb  = (unsigned short*)(ws + 167772160);      //  33,554,432 B
    unsigned short* mixb  = (unsigned short*)(ws + 201326592);      //  33,554,432 B
    unsigned short* Wab   = (unsigned short*)(ws + 234881024);      //   1,048,576 B
    unsigned short* Wdb   = (unsigned short*)(ws + 235929600);      //     524,288 B
    unsigned short* hb    = (unsigned short*)(ws + 236453888);      //     131,072 B
    unsigned int*   flags = (unsigned int*)(ws + 236584960);        //      65,536 B

    // zero h double-buffers + flags (ws is re-poisoned 0xAA before every launch)
    hipMemsetAsync(ws + 236453888, 0, 196608, stream);

    k_cvt<<<1024, 256, 0, stream>>>(enc_f, encb, 16777216 / 8);
    k_cvt<<<256, 256, 0, stream>>>(W_a, Wab, 524288 / 8);
    k_cvt<<<128, 256, 0, stream>>>(W_d, Wdb, 262144 / 8);
    k_transpose<<<dim3(64, 8, 8), dim3(64, 4), 0, stream>>>(encb, encT);
    k_gemm_xi<<<dim3(256, 12), 256, 0, stream>>>(emb, W_ih, b_ih, xi);
    k_scan<<<32, 1024, 0, stream>>>(W_hh, b_hh, xi, decb, out + 16777216, hb, flags);
    k_attn<<<512, 256, 0, stream>>>(decb, encb, encT, masks, mixb);
    k_out<<<512, 256, 0, stream>>>(mixb, decb, Wab, b_a, Wdb, b_d, out);
}